// Round 1
// baseline (410.168 us; speedup 1.0000x reference)
//
#include <hip/hip_runtime.h>
#include <hip/hip_bf16.h>

using bf16 = __hip_bfloat16;
typedef __attribute__((ext_vector_type(8))) short bf16x8;   // MFMA A/B frag (guide §3)
typedef __attribute__((ext_vector_type(4))) float f32x4;    // MFMA C/D frag
typedef __attribute__((ext_vector_type(4))) unsigned short us4;

#define GAS __attribute__((address_space(1)))
#define LAS __attribute__((address_space(3)))

__device__ __forceinline__ void gload_lds16(const bf16* g, bf16* lds) {
  // async global->LDS, 16B/lane; LDS dest = wave-uniform base + lane*16 (guide §5)
  __builtin_amdgcn_global_load_lds((const GAS void*)g, (LAS void*)lds, 16, 0, 0);
}

// ---------------- compaction: group sample indices by domain ----------------
__global__ void zero_meta_k(int* meta) {
  int t = threadIdx.x;
  if (t < 12) meta[t] = 0;   // [0..2]=cnt  [4..6]=base  [8..10]=cursor
}
__global__ void count_k(const int* __restrict__ lab, int* meta, int B) {
  int i = blockIdx.x * 256 + threadIdx.x;
  if (i < B) atomicAdd(&meta[lab[i]], 1);
}
__global__ void bases_k(int* meta) {
  meta[4] = 0; meta[5] = meta[0]; meta[6] = meta[0] + meta[1];
}
__global__ void scatter_k(const int* __restrict__ lab, int* meta, int* perm, int B) {
  int i = blockIdx.x * 256 + threadIdx.x;
  if (i < B) {
    int d = lab[i];
    int pos = meta[4 + d] + atomicAdd(&meta[8 + d], 1);
    perm[pos] = i;
  }
}

// ---------------- dtype conversions ----------------
__global__ __launch_bounds__(256) void cvt_bf16_k(const float* __restrict__ in,
                                                  bf16* __restrict__ out, int n4) {
  int i = blockIdx.x * 256 + threadIdx.x;
  if (i >= n4) return;
  float4 v = ((const float4*)in)[i];
  bf16 t[4] = {__float2bfloat16(v.x), __float2bfloat16(v.y),
               __float2bfloat16(v.z), __float2bfloat16(v.w)};
  ((us4*)out)[i] = *(const us4*)t;
}

// text (1380x1024) -> bf16 padded to 1408 rows (pad zero; stores predicated anyway)
__global__ __launch_bounds__(256) void cvt_text_k(const float* __restrict__ in,
                                                  bf16* __restrict__ out) {
  int i = blockIdx.x * 256 + threadIdx.x;          // over 1408*1024/4
  const int n4v = 1380 * 1024 / 4;
  if (i >= 1408 * 1024 / 4) return;
  if (i < n4v) {
    float4 v = ((const float4*)in)[i];
    bf16 t[4] = {__float2bfloat16(v.x), __float2bfloat16(v.y),
                 __float2bfloat16(v.z), __float2bfloat16(v.w)};
    ((us4*)out)[i] = *(const us4*)t;
  } else {
    us4 z = {0, 0, 0, 0};
    ((us4*)out)[i] = z;
  }
}

// W1 [3][1024][256] -> W1T [3][256][1024] bf16   (out[d][r][k] = in[d][k][r])
__global__ __launch_bounds__(256) void cvt_w1t_k(const float* __restrict__ W1,
                                                 bf16* __restrict__ W1T) {
  int i = blockIdx.x * 256 + threadIdx.x;
  if (i >= 3 * 256 * 1024) return;
  int d = i >> 18, rem = i & 262143;
  int r = rem >> 10, k = rem & 1023;
  W1T[i] = __float2bfloat16(W1[(size_t)d * 262144 + (size_t)k * 256 + r]);
}
// W2 [3][256][1024] -> W2T [3][1024][256] bf16   (out[d][n][k] = in[d][k][n])
__global__ __launch_bounds__(256) void cvt_w2t_k(const float* __restrict__ W2,
                                                 bf16* __restrict__ W2T) {
  int i = blockIdx.x * 256 + threadIdx.x;
  if (i >= 3 * 1024 * 256) return;
  int d = i >> 18, rem = i & 262143;
  int n = rem >> 8, k = rem & 255;
  W2T[i] = __float2bfloat16(W2[(size_t)d * 262144 + (size_t)k * 1024 + n]);
}

// ---------------- m97-style bf16 GEMM:  C = A @ BT^T ----------------
// 128x128 tile, BK=32, 256 thr = 4 waves (2x2), each wave 64x64 = 4x4 16x16 frags.
template <bool SEG, bool GATHER_A, bool SCATTER_C, bool RELU, bool C_BF16, bool SCALE>
__global__ __launch_bounds__(256) void gemm_bt(
    const bf16* __restrict__ A, const bf16* __restrict__ BT, void* __restrict__ Cv,
    const int* __restrict__ perm, const int* __restrict__ meta, int Mfull, int N,
    int K, int ldc, int Nvalid, const float* __restrict__ scale_ptr) {
  int cnt = Mfull, base = 0;
  if (SEG) {
    int dom = blockIdx.z;
    cnt = meta[dom];
    base = meta[4 + dom];
    BT += (size_t)dom * N * K;
  }
  const int m0 = blockIdx.x * 128;
  if (m0 >= cnt) return;           // dynamic-M early exit
  const int n0 = blockIdx.y * 128;

  __shared__ bf16 sA[2][128][32];
  __shared__ bf16 sB[2][128][32];

  const int tid = threadIdx.x;
  const int wid = tid >> 6;
  const int lane = tid & 63;

  // staging coords: lane l -> row wid*16 + l/4 (+64 for 2nd iter), k-off (l&3)*8
  const int srow = (wid << 4) + (lane >> 2);
  const int skoff = (lane & 3) << 3;

  int p0 = m0 + srow;       if (p0 > cnt - 1) p0 = cnt - 1;
  int p1 = m0 + srow + 64;  if (p1 > cnt - 1) p1 = cnt - 1;
  long ar0, ar1;
  if (GATHER_A) { ar0 = perm[base + p0]; ar1 = perm[base + p1]; }
  else          { ar0 = base + p0;       ar1 = base + p1; }
  const bf16* a0 = A + (size_t)ar0 * K + skoff;
  const bf16* a1 = A + (size_t)ar1 * K + skoff;
  const bf16* b0 = BT + (size_t)(n0 + srow) * K + skoff;
  const bf16* b1 = BT + (size_t)(n0 + srow + 64) * K + skoff;

  const int fr = lane & 15;   // frag col (C) / A row / B col
  const int fq = lane >> 4;   // k-quarter; C row block = fq*4

  f32x4 acc[4][4];
#pragma unroll
  for (int m = 0; m < 4; ++m)
#pragma unroll
    for (int n = 0; n < 4; ++n) acc[m][n] = (f32x4){0.f, 0.f, 0.f, 0.f};

  const int nk = K >> 5;
  auto stage = [&](int buf, int kt) {
    gload_lds16(a0 + kt * 32, &sA[buf][wid * 16][0]);
    gload_lds16(a1 + kt * 32, &sA[buf][wid * 16 + 64][0]);
    gload_lds16(b0 + kt * 32, &sB[buf][wid * 16][0]);
    gload_lds16(b1 + kt * 32, &sB[buf][wid * 16 + 64][0]);
  };

  stage(0, 0);
  __syncthreads();
  const int wr = wid >> 1, wc = wid & 1;
  for (int kt = 0; kt < nk; ++kt) {
    const int cur = kt & 1;
    if (kt + 1 < nk) stage(cur ^ 1, kt + 1);
    bf16x8 af[4], bfr[4];
#pragma unroll
    for (int m = 0; m < 4; ++m)
      af[m] = *(const bf16x8*)&sA[cur][wr * 64 + m * 16 + fr][fq * 8];
#pragma unroll
    for (int n = 0; n < 4; ++n)
      bfr[n] = *(const bf16x8*)&sB[cur][wc * 64 + n * 16 + fr][fq * 8];
#pragma unroll
    for (int m = 0; m < 4; ++m)
#pragma unroll
      for (int n = 0; n < 4; ++n)
        acc[m][n] = __builtin_amdgcn_mfma_f32_16x16x32_bf16(af[m], bfr[n], acc[m][n], 0, 0, 0);
    __syncthreads();
  }

  float s = 1.f;
  if (SCALE) s = expf(*scale_ptr);
#pragma unroll
  for (int m = 0; m < 4; ++m) {
#pragma unroll
    for (int r = 0; r < 4; ++r) {
      const int p = m0 + wr * 64 + m * 16 + fq * 4 + r;
      if (p < cnt) {
        size_t crow;
        if (SCATTER_C) crow = perm[base + p];
        else if (SEG)  crow = base + p;
        else           crow = p;
#pragma unroll
        for (int n = 0; n < 4; ++n) {
          const int col = n0 + wc * 64 + n * 16 + fr;
          if (col < Nvalid) {
            float v = acc[m][n][r];
            if (RELU) v = fmaxf(v, 0.f);
            v *= s;
            if (C_BF16) ((bf16*)Cv)[crow * (size_t)ldc + col] = __float2bfloat16(v);
            else        ((float*)Cv)[crow * (size_t)ldc + col] = v;
          }
        }
      }
    }
  }
}

// ---------------- fused = normalize(0.2*a + 0.8*x), in place over a (bf16) ------------
__global__ __launch_bounds__(256) void fuse_norm_k(const float* __restrict__ x,
                                                   bf16* __restrict__ F) {
  const int row = blockIdx.x;
  const int t = threadIdx.x;
  const size_t roff = (size_t)row * 1024;
  float f[4];
  float ss = 0.f;
#pragma unroll
  for (int j = 0; j < 4; ++j) {
    const int c = t + j * 256;
    float a = __bfloat162float(F[roff + c]);
    float xv = x[roff + c];
    f[j] = 0.2f * a + 0.8f * xv;
    ss += f[j] * f[j];
  }
#pragma unroll
  for (int o = 32; o > 0; o >>= 1) ss += __shfl_down(ss, o);
  __shared__ float sred[4];
  if ((t & 63) == 0) sred[t >> 6] = ss;
  __syncthreads();
  const float rinv = 1.0f / sqrtf(sred[0] + sred[1] + sred[2] + sred[3]);
#pragma unroll
  for (int j = 0; j < 4; ++j) {
    const int c = t + j * 256;
    F[roff + c] = __float2bfloat16(f[j] * rinv);
  }
}

extern "C" void kernel_launch(void* const* d_in, const int* in_sizes, int n_in,
                              void* d_out, int out_size, void* d_ws, size_t ws_size,
                              hipStream_t stream) {
  (void)in_sizes; (void)n_in; (void)out_size; (void)ws_size;
  const float* x    = (const float*)d_in[0];
  const int*   lab  = (const int*)d_in[1];
  const float* W1   = (const float*)d_in[2];
  const float* W2   = (const float*)d_in[3];
  const float* text = (const float*)d_in[4];
  const float* lsc  = (const float*)d_in[5];
  float* out = (float*)d_out;

  const int B = 16384, D = 1024, R = 256, NT = 1380, NTP = 1408;

  char* p = (char*)d_ws;
  auto carve = [&](size_t bytes) {
    char* r = p;
    p += (bytes + 255) & ~(size_t)255;
    return r;
  };
  int*  meta = (int*)carve(64);
  int*  perm = (int*)carve((size_t)B * 4);
  bf16* Xb   = (bf16*)carve((size_t)B * D * 2);     // reused as Fb after GEMM1
  bf16* W1T  = (bf16*)carve((size_t)3 * R * D * 2);
  bf16* W2T  = (bf16*)carve((size_t)3 * D * R * 2);
  bf16* Tb   = (bf16*)carve((size_t)NTP * D * 2);
  bf16* H    = (bf16*)carve((size_t)B * R * 2);
  bf16* Fb   = Xb;   // alias: Xb dead after GEMM1

  zero_meta_k<<<1, 64, 0, stream>>>(meta);
  count_k<<<B / 256, 256, 0, stream>>>(lab, meta, B);
  bases_k<<<1, 1, 0, stream>>>(meta);
  scatter_k<<<B / 256, 256, 0, stream>>>(lab, meta, perm, B);

  cvt_bf16_k<<<(B * D / 4 + 255) / 256, 256, 0, stream>>>(x, Xb, B * D / 4);
  cvt_w1t_k<<<(3 * R * D + 255) / 256, 256, 0, stream>>>(W1, W1T);
  cvt_w2t_k<<<(3 * R * D + 255) / 256, 256, 0, stream>>>(W2, W2T);
  cvt_text_k<<<(NTP * D / 4 + 255) / 256, 256, 0, stream>>>(text, Tb);

  // GEMM1: H[perm-pos] = relu(Xb[perm] @ W1T[dom]^T)   M=cnt  N=256 K=1024
  dim3 g1(128, 2, 3);
  gemm_bt<true, true, false, true, true, false><<<g1, 256, 0, stream>>>(
      Xb, W1T, H, perm, meta, B, R, D, R, R, nullptr);
  // GEMM2: Fb[orig] = relu(H @ W2T[dom]^T)  (scatter)  M=cnt  N=1024 K=256
  dim3 g2(128, 8, 3);
  gemm_bt<true, false, true, true, true, false><<<g2, 256, 0, stream>>>(
      H, W2T, Fb, perm, meta, B, D, R, D, D, nullptr);
  // fuse + row-normalize (in place, bf16 out)
  fuse_norm_k<<<B, 256, 0, stream>>>(x, Fb);
  // GEMM3: out = exp(ls) * Fb @ Tb^T   M=16384 N=1380(padded 1408) K=1024, f32 out
  dim3 g3(128, 11, 1);
  gemm_bt<false, false, false, false, false, true><<<g3, 256, 0, stream>>>(
      Fb, Tb, out, nullptr, nullptr, B, NTP, D, NT, NT, lsc);
}

// Round 2
// 188.490 us; speedup vs baseline: 2.1761x; 2.1761x over previous
//
#include <hip/hip_runtime.h>
#include <hip/hip_bf16.h>

using bf16 = __hip_bfloat16;
typedef __attribute__((ext_vector_type(8))) short bf16x8;   // MFMA A/B frag (guide §3)
typedef __attribute__((ext_vector_type(4))) float f32x4;    // MFMA C/D frag
typedef __attribute__((ext_vector_type(4))) unsigned short us4;

#define GAS __attribute__((address_space(1)))
#define LAS __attribute__((address_space(3)))

__device__ __forceinline__ void gload_lds16(const bf16* g, bf16* lds) {
  // async global->LDS, 16B/lane; LDS dest = wave-uniform base + lane*16 (guide §5)
  __builtin_amdgcn_global_load_lds((const GAS void*)g, (LAS void*)lds, 16, 0, 0);
}

// ---------------- compaction: group sample indices by domain (atomic-free) --------
// B=16384 = 64 blocks * 256 threads. Stable (index-ordered) => deterministic perm.
__global__ __launch_bounds__(256) void hist_k(const int* __restrict__ lab,
                                              int* __restrict__ blockHist) {
  const int blk = blockIdx.x, t = threadIdx.x;
  const int lane = t & 63, w = t >> 6;
  const int d = lab[blk * 256 + t];
  __shared__ int wc[4][3];
#pragma unroll
  for (int dd = 0; dd < 3; ++dd) {
    unsigned long long m = __ballot(d == dd);
    if (lane == 0) wc[w][dd] = __popcll(m);
  }
  __syncthreads();
  if (t < 3) blockHist[blk * 3 + t] = wc[0][t] + wc[1][t] + wc[2][t] + wc[3][t];
}

// one block: exclusive prefix over 64 blocks x 3 domains; meta[0..2]=cnt meta[4..6]=base
__global__ __launch_bounds__(256) void scan_k(const int* __restrict__ blockHist,
                                              int* __restrict__ blockOff,
                                              int* __restrict__ meta) {
  __shared__ int h[64][3];
  __shared__ int tot[3];
  const int t = threadIdx.x;
  if (t < 192) h[t / 3][t % 3] = blockHist[t];
  __syncthreads();
  if (t < 3) {
    int s = 0;
    for (int b = 0; b < 64; ++b) { int v = h[b][t]; h[b][t] = s; s += v; }
    tot[t] = s;
    meta[t] = s;
  }
  __syncthreads();
  if (t == 0) { meta[4] = 0; meta[5] = tot[0]; meta[6] = tot[0] + tot[1]; }
  if (t < 192) {
    int b = t / 3, d = t % 3;
    int base = (d == 0) ? 0 : (d == 1 ? tot[0] : tot[0] + tot[1]);
    blockOff[t] = base + h[b][d];
  }
}

__global__ __launch_bounds__(256) void scatter2_k(const int* __restrict__ lab,
                                                  const int* __restrict__ blockOff,
                                                  int* __restrict__ perm) {
  const int blk = blockIdx.x, t = threadIdx.x;
  const int lane = t & 63, w = t >> 6;
  const int i = blk * 256 + t;
  const int d = lab[i];
  __shared__ int wc[4][3];
  unsigned long long mymask = 0;
#pragma unroll
  for (int dd = 0; dd < 3; ++dd) {
    unsigned long long m = __ballot(d == dd);
    if (lane == 0) wc[w][dd] = __popcll(m);
    if (dd == d) mymask = m;
  }
  __syncthreads();
  int woff = 0;
  for (int ww = 0; ww < w; ++ww) woff += wc[ww][d];
  const unsigned long long lt = ((unsigned long long)1 << lane) - 1;
  const int rank = blockOff[blk * 3 + d] + woff + __popcll(mymask & lt);
  perm[rank] = i;
}

// ---------------- dtype conversions ----------------
__global__ __launch_bounds__(256) void cvt_bf16_k(const float* __restrict__ in,
                                                  bf16* __restrict__ out, int n4) {
  int i = blockIdx.x * 256 + threadIdx.x;
  if (i >= n4) return;
  float4 v = ((const float4*)in)[i];
  bf16 t[4] = {__float2bfloat16(v.x), __float2bfloat16(v.y),
               __float2bfloat16(v.z), __float2bfloat16(v.w)};
  ((us4*)out)[i] = *(const us4*)t;
}

// text (1380x1024) -> bf16 padded to 1408 rows (pad zero)
__global__ __launch_bounds__(256) void cvt_text_k(const float* __restrict__ in,
                                                  bf16* __restrict__ out) {
  int i = blockIdx.x * 256 + threadIdx.x;          // over 1408*1024/4
  const int n4v = 1380 * 1024 / 4;
  if (i >= 1408 * 1024 / 4) return;
  if (i < n4v) {
    float4 v = ((const float4*)in)[i];
    bf16 t[4] = {__float2bfloat16(v.x), __float2bfloat16(v.y),
                 __float2bfloat16(v.z), __float2bfloat16(v.w)};
    ((us4*)out)[i] = *(const us4*)t;
  } else {
    us4 z = {0, 0, 0, 0};
    ((us4*)out)[i] = z;
  }
}

// W1 [3][1024][256] -> W1T [3][256][1024] bf16   (out[d][r][k] = in[d][k][r])
__global__ __launch_bounds__(256) void cvt_w1t_k(const float* __restrict__ W1,
                                                 bf16* __restrict__ W1T) {
  int i = blockIdx.x * 256 + threadIdx.x;
  if (i >= 3 * 256 * 1024) return;
  int d = i >> 18, rem = i & 262143;
  int r = rem >> 10, k = rem & 1023;
  W1T[i] = __float2bfloat16(W1[(size_t)d * 262144 + (size_t)k * 256 + r]);
}
// W2 [3][256][1024] -> W2T [3][1024][256] bf16   (out[d][n][k] = in[d][k][n])
__global__ __launch_bounds__(256) void cvt_w2t_k(const float* __restrict__ W2,
                                                 bf16* __restrict__ W2T) {
  int i = blockIdx.x * 256 + threadIdx.x;
  if (i >= 3 * 1024 * 256) return;
  int d = i >> 18, rem = i & 262143;
  int n = rem >> 8, k = rem & 255;
  W2T[i] = __float2bfloat16(W2[(size_t)d * 262144 + (size_t)k * 1024 + n]);
}

// ---------------- m97-style bf16 GEMM:  C = A @ BT^T ----------------
// 128x128 tile, BK=32, 256 thr = 4 waves (2x2), each wave 64x64 = 4x4 16x16 frags.
template <bool SEG, bool GATHER_A, bool SCATTER_C, bool RELU, bool C_BF16, bool SCALE>
__global__ __launch_bounds__(256) void gemm_bt(
    const bf16* __restrict__ A, const bf16* __restrict__ BT, void* __restrict__ Cv,
    const int* __restrict__ perm, const int* __restrict__ meta, int Mfull, int N,
    int K, int ldc, int Nvalid, const float* __restrict__ scale_ptr) {
  int cnt = Mfull, base = 0;
  if (SEG) {
    int dom = blockIdx.z;
    cnt = meta[dom];
    base = meta[4 + dom];
    BT += (size_t)dom * N * K;
  }
  const int m0 = blockIdx.x * 128;
  if (m0 >= cnt) return;           // dynamic-M early exit
  const int n0 = blockIdx.y * 128;

  __shared__ bf16 sA[2][128][32];
  __shared__ bf16 sB[2][128][32];

  const int tid = threadIdx.x;
  const int wid = tid >> 6;
  const int lane = tid & 63;

  // staging coords: lane l -> row wid*16 + l/4 (+64 for 2nd iter), k-off (l&3)*8
  const int srow = (wid << 4) + (lane >> 2);
  const int skoff = (lane & 3) << 3;

  int p0 = m0 + srow;       if (p0 > cnt - 1) p0 = cnt - 1;
  int p1 = m0 + srow + 64;  if (p1 > cnt - 1) p1 = cnt - 1;
  long ar0, ar1;
  if (GATHER_A) { ar0 = perm[base + p0]; ar1 = perm[base + p1]; }
  else          { ar0 = base + p0;       ar1 = base + p1; }
  const bf16* a0 = A + (size_t)ar0 * K + skoff;
  const bf16* a1 = A + (size_t)ar1 * K + skoff;
  const bf16* b0 = BT + (size_t)(n0 + srow) * K + skoff;
  const bf16* b1 = BT + (size_t)(n0 + srow + 64) * K + skoff;

  const int fr = lane & 15;   // frag col (C) / A row / B col
  const int fq = lane >> 4;   // k-quarter; C row block = fq*4

  f32x4 acc[4][4];
#pragma unroll
  for (int m = 0; m < 4; ++m)
#pragma unroll
    for (int n = 0; n < 4; ++n) acc[m][n] = (f32x4){0.f, 0.f, 0.f, 0.f};

  const int nk = K >> 5;
  auto stage = [&](int buf, int kt) {
    gload_lds16(a0 + kt * 32, &sA[buf][wid * 16][0]);
    gload_lds16(a1 + kt * 32, &sA[buf][wid * 16 + 64][0]);
    gload_lds16(b0 + kt * 32, &sB[buf][wid * 16][0]);
    gload_lds16(b1 + kt * 32, &sB[buf][wid * 16 + 64][0]);
  };

  stage(0, 0);
  __syncthreads();
  const int wr = wid >> 1, wc = wid & 1;
  for (int kt = 0; kt < nk; ++kt) {
    const int cur = kt & 1;
    if (kt + 1 < nk) stage(cur ^ 1, kt + 1);
    bf16x8 af[4], bfr[4];
#pragma unroll
    for (int m = 0; m < 4; ++m)
      af[m] = *(const bf16x8*)&sA[cur][wr * 64 + m * 16 + fr][fq * 8];
#pragma unroll
    for (int n = 0; n < 4; ++n)
      bfr[n] = *(const bf16x8*)&sB[cur][wc * 64 + n * 16 + fr][fq * 8];
#pragma unroll
    for (int m = 0; m < 4; ++m)
#pragma unroll
      for (int n = 0; n < 4; ++n)
        acc[m][n] = __builtin_amdgcn_mfma_f32_16x16x32_bf16(af[m], bfr[n], acc[m][n], 0, 0, 0);
    __syncthreads();
  }

  float s = 1.f;
  if (SCALE) s = expf(*scale_ptr);
#pragma unroll
  for (int m = 0; m < 4; ++m) {
#pragma unroll
    for (int r = 0; r < 4; ++r) {
      const int p = m0 + wr * 64 + m * 16 + fq * 4 + r;
      if (p < cnt) {
        size_t crow;
        if (SCATTER_C) crow = perm[base + p];
        else if (SEG)  crow = base + p;
        else           crow = p;
#pragma unroll
        for (int n = 0; n < 4; ++n) {
          const int col = n0 + wc * 64 + n * 16 + fr;
          if (col < Nvalid) {
            float v = acc[m][n][r];
            if (RELU) v = fmaxf(v, 0.f);
            v *= s;
            if (C_BF16) ((bf16*)Cv)[crow * (size_t)ldc + col] = __float2bfloat16(v);
            else        ((float*)Cv)[crow * (size_t)ldc + col] = v;
          }
        }
      }
    }
  }
}

// ---------------- fused = normalize(0.2*a + 0.8*x), in place over a (bf16) ------------
__global__ __launch_bounds__(256) void fuse_norm_k(const float* __restrict__ x,
                                                   bf16* __restrict__ F) {
  const int row = blockIdx.x;
  const int t = threadIdx.x;
  const size_t roff = (size_t)row * 1024;
  float f[4];
  float ss = 0.f;
#pragma unroll
  for (int j = 0; j < 4; ++j) {
    const int c = t + j * 256;
    float a = __bfloat162float(F[roff + c]);
    float xv = x[roff + c];
    f[j] = 0.2f * a + 0.8f * xv;
    ss += f[j] * f[j];
  }
#pragma unroll
  for (int o = 32; o > 0; o >>= 1) ss += __shfl_down(ss, o);
  __shared__ float sred[4];
  if ((t & 63) == 0) sred[t >> 6] = ss;
  __syncthreads();
  const float rinv = 1.0f / sqrtf(sred[0] + sred[1] + sred[2] + sred[3]);
#pragma unroll
  for (int j = 0; j < 4; ++j) {
    const int c = t + j * 256;
    F[roff + c] = __float2bfloat16(f[j] * rinv);
  }
}

extern "C" void kernel_launch(void* const* d_in, const int* in_sizes, int n_in,
                              void* d_out, int out_size, void* d_ws, size_t ws_size,
                              hipStream_t stream) {
  (void)in_sizes; (void)n_in; (void)out_size; (void)ws_size;
  const float* x    = (const float*)d_in[0];
  const int*   lab  = (const int*)d_in[1];
  const float* W1   = (const float*)d_in[2];
  const float* W2   = (const float*)d_in[3];
  const float* text = (const float*)d_in[4];
  const float* lsc  = (const float*)d_in[5];
  float* out = (float*)d_out;

  const int B = 16384, D = 1024, R = 256, NT = 1380, NTP = 1408;

  char* p = (char*)d_ws;
  auto carve = [&](size_t bytes) {
    char* r = p;
    p += (bytes + 255) & ~(size_t)255;
    return r;
  };
  int*  meta  = (int*)carve(64);
  int*  bhist = (int*)carve(64 * 3 * 4);
  int*  boff  = (int*)carve(64 * 3 * 4);
  int*  perm  = (int*)carve((size_t)B * 4);
  bf16* Xb    = (bf16*)carve((size_t)B * D * 2);     // reused as Fb after GEMM1
  bf16* W1T   = (bf16*)carve((size_t)3 * R * D * 2);
  bf16* W2T   = (bf16*)carve((size_t)3 * D * R * 2);
  bf16* Tb    = (bf16*)carve((size_t)NTP * D * 2);
  bf16* H     = (bf16*)carve((size_t)B * R * 2);
  bf16* Fb    = Xb;   // alias: Xb dead after GEMM1

  hist_k<<<B / 256, 256, 0, stream>>>(lab, bhist);
  scan_k<<<1, 256, 0, stream>>>(bhist, boff, meta);
  scatter2_k<<<B / 256, 256, 0, stream>>>(lab, boff, perm);

  cvt_bf16_k<<<(B * D / 4 + 255) / 256, 256, 0, stream>>>(x, Xb, B * D / 4);
  cvt_w1t_k<<<(3 * R * D + 255) / 256, 256, 0, stream>>>(W1, W1T);
  cvt_w2t_k<<<(3 * R * D + 255) / 256, 256, 0, stream>>>(W2, W2T);
  cvt_text_k<<<(NTP * D / 4 + 255) / 256, 256, 0, stream>>>(text, Tb);

  // GEMM1: H[perm-pos] = relu(Xb[perm] @ W1T[dom]^T)   M=cnt  N=256 K=1024
  dim3 g1(128, 2, 3);
  gemm_bt<true, true, false, true, true, false><<<g1, 256, 0, stream>>>(
      Xb, W1T, H, perm, meta, B, R, D, R, R, nullptr);
  // GEMM2: Fb[orig] = relu(H @ W2T[dom]^T)  (scatter)  M=cnt  N=1024 K=256
  dim3 g2(128, 8, 3);
  gemm_bt<true, false, true, true, true, false><<<g2, 256, 0, stream>>>(
      H, W2T, Fb, perm, meta, B, D, R, D, D, nullptr);
  // fuse + row-normalize (in place, bf16 out)
  fuse_norm_k<<<B, 256, 0, stream>>>(x, Fb);
  // GEMM3: out = exp(ls) * Fb @ Tb^T   M=16384 N=1380(padded 1408) K=1024, f32 out
  dim3 g3(128, 11, 1);
  gemm_bt<false, false, false, false, false, true><<<g3, 256, 0, stream>>>(
      Fb, Tb, out, nullptr, nullptr, B, NTP, D, NT, NT, lsc);
}